// Round 15
// baseline (209.169 us; speedup 1.0000x reference)
//
#include <hip/hip_runtime.h>
#include <hip/hip_bf16.h>

// Problem constants
#define B_    8
#define C_    96
#define N_    3136      // 56*56
#define COUT_ 192
#define NTOK_ 25088     // B_*N_
#define BN_EPS 1e-5f

#define CROW 200        // conv cat LDS token-row stride in bf16 (192+8): 400B odd*16 -> conflict-free
#define BNC  (B_ * N_ * C_)
#define NT98  98        // 32-row K tiles per batch (3136/32)

// R26 K2 work decomposition: flat 768-block grid (exactly 3/CU, all
// resident) over a global tile queue of 200 (b,qb) pairs x 98 tiles.
#define NPAIR 200
#define TILES_TOTAL (NPAIR * NT98)   // 19600
#define NBLK2 768

// K2 LDS per buffer: Kh frags 6KB (frag kc at kc*1024, lane*16 within) |
// V 8KB at +6144 (96 ch x 80B rows + pad). x2 buffers = 28672 B.
#define K2_V_OFF 6144
#define K2_BUFSZ 14336

typedef __hip_bfloat16 bf16;
typedef unsigned short u16;
typedef unsigned int u32;
typedef __attribute__((ext_vector_type(8))) short short8;    // 8 bf16 = 16B (MFMA A/B frag)
typedef __attribute__((ext_vector_type(16))) float f32x16;   // 32x32 MFMA C/D frag

__device__ __forceinline__ u16 f2bf(float f) {
    union { __hip_bfloat16 h; u16 u; } cv;
    cv.h = __float2bfloat16(f);
    return cv.u;
}
__device__ __forceinline__ float bf2f(u16 v) {
    union { u16 u; __hip_bfloat16 h; } cv;
    cv.u = v;
    return __bfloat162float(cv.h);
}
__device__ __forceinline__ u32 packbf2(float lo, float hi) {
    return ((u32)f2bf(hi) << 16) | (u32)f2bf(lo);
}

// async global->LDS DMA, 16B per lane: LDS dest = WAVE-UNIFORM base + lane*16.
__device__ __forceinline__ void gload_lds16(const void* g, void* l) {
    __builtin_amdgcn_global_load_lds((const __attribute__((address_space(1))) void*)g,
                                     (__attribute__((address_space(3))) void*)l,
                                     16, 0, 0);
}

// fragment offset in xf arrays: frag (b-pre-offset pointer, tile t, chunk kc)
// = ((t*6)+kc) * 512 u16 (1KB). Lane l holds token t*32+(l&31),
// channels kc*16+(l>>5)*8 .. +8 — exactly the mfma_32x32x16 A/B layout.
__device__ __forceinline__ size_t foff(int t, int kc) {
    return ((size_t)t * 6 + kc) << 9;
}

// ---------------------------------------------------------------------------
// K1: x [B][C][N] fp32 ->
//   xf_hi/xf_lo [B][98][6][512] bf16 fragment-major (K and Q frags, hi/lo)
//   xc_hi [B][C][N] bf16 (channel-major, V staged from here)
//   norm2 per-token squared norms.  (R20 version — HW-verified.)
__global__ __launch_bounds__(256) void transpose_split(const float* __restrict__ x,
                                                       u16* __restrict__ xf_hi,
                                                       u16* __restrict__ xf_lo,
                                                       u16* __restrict__ xc_hi,
                                                       float* __restrict__ norm2) {
    __shared__ float tile[32][33];
    __shared__ float nrm[32];
    const int nb = blockIdx.x * 32;     // token base (tile t = nb/32)
    const int cb = blockIdx.y * 32;     // channel base (kc = cb/16 + {0,1})
    const int b  = blockIdx.z;
    const int tid = threadIdx.x;
    const int tx = tid & 31;
    const int ty = tid >> 5;
    if (tid < 32) nrm[tid] = 0.0f;
    float psum = 0.0f;
#pragma unroll
    for (int r = 0; r < 32; r += 8) {
        size_t idx = ((size_t)b * C_ + cb + ty + r) * N_ + nb + tx;
        float v = x[idx];
        tile[ty + r][tx] = v;
        xc_hi[idx] = f2bf(v);
        psum = fmaf(v, v, psum);
    }
    __syncthreads();               // tile visible; nrm init done
    atomicAdd(&nrm[tx], psum);     // LDS atomic, 8 adders per slot

    // phase 2: fragment-major hi/lo writes. 128 items (kc_i in 0..1, lane l
    // in 0..63); threads 0-127 write hi, 128-255 write lo. 16B/thread.
    {
        const int item  = tid & 127;
        const int is_lo = tid >> 7;
        const int kc_i  = item >> 6;
        const int l     = item & 63;
        const int kcg   = (cb >> 4) + kc_i;
        union { u16 a[8]; short8 v8; } o;
#pragma unroll
        for (int j = 0; j < 8; j++) {
            float v = tile[kc_i * 16 + ((l >> 5) * 8) + j][l & 31];
            u16 h = f2bf(v);
            o.a[j] = is_lo ? f2bf(v - bf2f(h)) : h;
        }
        u16* dst = (is_lo ? xf_lo : xf_hi) +
                   ((size_t)b * NT98 * 6 << 9) + foff(nb >> 5, kcg) + l * 8;
        *(short8*)dst = o.v8;
    }
    __syncthreads();               // nrm complete
    if (tid < 32)
        atomicAdd(&norm2[(size_t)b * N_ + nb + tid], nrm[tid]);
}

// K1b: conv_w [O][2C] fp32 -> wf_hi/wf_lo bf16 FRAGMENT-MAJOR (R23, verified).
__global__ __launch_bounds__(256) void cast_w(const float* __restrict__ w,
                                              u16* __restrict__ wf_hi,
                                              u16* __restrict__ wf_lo) {
    int i = blockIdx.x * 256 + threadIdx.x;
    if (i >= COUT_ * 2 * C_) return;
    float v = w[i];
    u16 h  = f2bf(v);
    u16 lo = f2bf(v - bf2f(h));
    int o = i / (2 * C_), c = i % (2 * C_);
    int mt = o >> 5, lrow = o & 31;
    int ks = c >> 4, hi8 = (c >> 3) & 1, j = c & 7;
    size_t d = ((size_t)(mt * 12 + ks) * 64 + hi8 * 32 + lrow) * 8 + j;
    wf_hi[d] = h;
    wf_lo[d] = lo;
}

// K1c: global max of norm2 — multi-block; norm2>=0 -> int-bits atomicMax.
__global__ __launch_bounds__(256) void norm_max(const float* __restrict__ norm2,
                                                int* __restrict__ maxbits) {
    const int tid = blockIdx.x * 256 + threadIdx.x;
    float m = 0.0f;
    for (int i = tid; i < NTOK_; i += gridDim.x * 256) m = fmaxf(m, norm2[i]);
#pragma unroll
    for (int d = 1; d < 64; d <<= 1) m = fmaxf(m, __shfl_xor(m, d));
    if ((threadIdx.x & 63) == 0) atomicMax(maxbits, __float_as_int(m));
}

// ---------------------------------------------------------------------------
// K2: MFMA flash attention, transposed-S. R26: BALANCED WORK QUEUE.
// R22's 600-block grid left 88 CUs with 3 resident blocks vs 168 with 2
// (78% balance; occ 19.5 measured). Flat 768-block grid (exactly 3/CU),
// block beta processes global tiles [beta*19600/768, (beta+1)*19600/768):
// pair = t/98 -> (b = pair/25, qb = pair%25), kt = t%98. A range crosses
// <=1 pair boundary: flush O/l atomics, reload Q frags + m_i, continue.
// Staging derives (batch,kt) from tile index -> double-buffer runs
// seamlessly across boundaries. Compute body identical to R21/R22.
__global__ __launch_bounds__(256, 3) void flash_attn_mfma32(const u16* __restrict__ xf_hi,
                                                            const u16* __restrict__ xf_lo,
                                                            const u16* __restrict__ xc_hi,
                                                            const float* __restrict__ norm2,
                                                            const int* __restrict__ maxbits,
                                                            float* __restrict__ attT,
                                                            float* __restrict__ l_arr) {
    __shared__ __align__(16) char LDSU[2][K2_BUFSZ];
    const int tid  = threadIdx.x;
    const int lane = tid & 63;
    const int w    = tid >> 6;
    const int col  = lane & 31;
    const int g    = lane >> 5;
    const int g16  = g * 16;

    const int beta = blockIdx.x;
    const int t0 = (int)(((long long)beta * TILES_TOTAL) / NBLK2);
    const int t1 = (int)(((long long)(beta + 1) * TILES_TOTAL) / NBLK2);

    // DMA slot offsets (batch-independent): Kh slots 0..5 contiguous 1KB,
    // V slots 6..13 (80B-row pattern). Wave w owns slots w+4j.
    u32 loff[4], dofs[4];
#pragma unroll
    for (int j = 0; j < 4; j++) {
        int s = w + 4 * j;
        if (s >= 14) { loff[j] = 0; dofs[j] = 0; continue; }
        if (s < 6) {
            loff[j] = (u32)(s * 1024 + lane * 16);
            dofs[j] = (u32)(s * 1024);
        } else {
            int t = s - 6;
            int p = t * 64 + lane;
            int ch = p / 5, c = p % 5;
            if (c > 3) c = 3;
            loff[j] = (ch < 96) ? (u32)(ch * (N_ * 2) + c * 16) : 0u;
            dofs[j] = (u32)(K2_V_OFF + t * 1024);
        }
    }

    const float maxn2 = __int_as_float(*maxbits);

    // pair state
    int pr = -1, b = 0, qrow = 0;
    const u16* fh = xf_hi;
    const u16* fl = xf_lo;
    short8 qh[6], ql[6];
    float m_i = 0.0f, l_acc = 0.0f;
    f32x16 O0, O1, O2;

    auto load_pair = [&](int np) {
        pr = np;
        b = pr / 25;
        int qb = pr % 25;
        fh = xf_hi + ((size_t)b * NT98 * 6 << 9);
        fl = xf_lo + ((size_t)b * NT98 * 6 << 9);
        int qt = qb * 4 + w;
        if (qt > NT98 - 1) qt = NT98 - 1;
        qrow = qb * 128 + w * 32 + col;
        const int qrowc = qrow < N_ ? qrow : N_ - 1;
#pragma unroll
        for (int kc = 0; kc < 6; kc++) {
            qh[kc] = *(const short8*)&fh[foff(qt, kc) + lane * 8];
            ql[kc] = *(const short8*)&fl[foff(qt, kc) + lane * 8];
        }
        m_i = sqrtf(norm2[(size_t)b * N_ + qrowc] * maxn2);
        l_acc = 0.0f;
#pragma unroll
        for (int i = 0; i < 16; i++) { O0[i] = 0.0f; O1[i] = 0.0f; O2[i] = 0.0f; }
    };

    auto flush = [&]() {
        if (qrow < N_) {
            float* ab = attT + (size_t)b * C_ * N_ + qrow;
#pragma unroll
            for (int r = 0; r < 16; r++) {
                int c = (r & 3) + 8 * (r >> 2) + 4 * g;
                atomicAdd(&ab[(size_t)(c)      * N_], O0[r]);
                atomicAdd(&ab[(size_t)(c + 32) * N_], O1[r]);
                atomicAdd(&ab[(size_t)(c + 64) * N_], O2[r]);
            }
            float l_tot = l_acc + __shfl_xor(l_acc, 32);
            if (g == 0) atomicAdd(&l_arr[(size_t)b * N_ + qrow], l_tot);
        }
    };

    // stage global tile t (Kh + V of tile's batch) into buffer nbuf
    auto stage = [&](int nbuf, int t) {
        const int tb = (t / NT98) / 25;
        const int kt = t % NT98;
        const char* sK = (const char*)(xf_hi + ((size_t)tb * NT98 * 6 << 9)) + (u32)kt * 6144u;
        const char* sV = (const char*)(xc_hi + (size_t)tb * C_ * N_) + (u32)kt * 64u;
#pragma unroll
        for (int j = 0; j < 4; j++) {
            int s = w + 4 * j;
            if (s >= 14) break;
            const char* sb = (s < 6) ? sK : sV;
            gload_lds16(sb + loff[j], (char*)&LDSU[nbuf][0] + dofs[j]);
        }
    };

    load_pair(t0 / NT98);
    stage(0, t0);
    __syncthreads();

    int buf = 0;
    for (int t = t0; t < t1; t++) {
        // (1) prefetch next tile (its own batch) into back buffer
        if (t + 1 < t1) stage(buf ^ 1, t + 1);

        const int kt = t % NT98;
        const char* Lb = (const char*)&LDSU[buf][0];

        // (2) Kl frags direct from global (coalesced, L1-hot)
        short8 kl[6];
#pragma unroll
        for (int kc = 0; kc < 6; kc++)
            kl[kc] = *(const short8*)&fl[foff(kt, kc) + lane * 8];

        // (3) QK^T: Kh from LDS (sequential lane*16 — conflict-free)
        f32x16 S = {0};
        __builtin_amdgcn_s_setprio(1);
#pragma unroll
        for (int kc = 0; kc < 6; kc++) {
            short8 kh = *(const short8*)(Lb + kc * 1024 + lane * 16);
            S = __builtin_amdgcn_mfma_f32_32x32x16_bf16(kh, ql[kc], S, 0, 0, 0);
            S = __builtin_amdgcn_mfma_f32_32x32x16_bf16(kl[kc], qh[kc], S, 0, 0, 0);
            S = __builtin_amdgcn_mfma_f32_32x32x16_bf16(kh, qh[kc], S, 0, 0, 0);
        }
        __builtin_amdgcn_s_setprio(0);

        // (4) softmax numerators + bf16 pack
        float p[16];
#pragma unroll
        for (int r = 0; r < 16; r++) {
            p[r] = __expf(S[r] - m_i);
            l_acc += p[r];
        }
        u32 w8[8];
#pragma unroll
        for (int q = 0; q < 8; q++) w8[q] = packbf2(p[2 * q], p[2 * q + 1]);

        // (5) PV from V-LDS (80B rows: conflict-free)
        __builtin_amdgcn_s_setprio(1);
#pragma unroll
        for (int kc = 0; kc < 2; kc++) {
            const int qb2 = kc * 4;
            u32 a0 = w8[qb2 + 0], a1 = w8[qb2 + 1];
            u32 a2 = w8[qb2 + 2], a3 = w8[qb2 + 3];
            u32 s0 = __shfl_xor((int)a0, 32), s1 = __shfl_xor((int)a1, 32);
            u32 s2 = __shfl_xor((int)a2, 32), s3 = __shfl_xor((int)a3, 32);
            union { short8 v; u32 u[4]; } Bf;
            Bf.u[0] = g ? s2 : a0;
            Bf.u[1] = g ? s3 : a1;
            Bf.u[2] = g ? a2 : s0;
            Bf.u[3] = g ? a3 : s1;
            const int vo = K2_V_OFF + col * 80 + kc * 32 + g16;
            short8 v0 = *(const short8*)(Lb + vo);
            short8 v1 = *(const short8*)(Lb + vo + 2560);   // +32 ch
            short8 v2 = *(const short8*)(Lb + vo + 5120);   // +64 ch
            O0 = __builtin_amdgcn_mfma_f32_32x32x16_bf16(v0, Bf.v, O0, 0, 0, 0);
            O1 = __builtin_amdgcn_mfma_f32_32x32x16_bf16(v1, Bf.v, O1, 0, 0, 0);
            O2 = __builtin_amdgcn_mfma_f32_32x32x16_bf16(v2, Bf.v, O2, 0, 0, 0);
        }
        __builtin_amdgcn_s_setprio(0);

        __syncthreads();     // drains my DMAs + all waves' LDS reads done
        buf ^= 1;

        // (6) pair boundary: flush previous pair, load next (uniform per block)
        if (t + 1 < t1) {
            int np = (t + 1) / NT98;
            if (np != pr) { flush(); load_pair(np); }
        }
    }
    flush();
}

// ---------------------------------------------------------------------------
// K3: MFMA 1x1 conv (R23 version — fragment-major weights, plain epilogue).
__global__ __launch_bounds__(128, 3) void conv_mfma(const float* __restrict__ x,
                                                    const float* __restrict__ attT,
                                                    const float* __restrict__ l_arr,
                                                    const u16* __restrict__ wf_hi,
                                                    const u16* __restrict__ wf_lo,
                                                    const float* __restrict__ convb,
                                                    float* __restrict__ y) {
    __shared__ u16 ch[32 * CROW];
    __shared__ u16 cl[32 * CROW];
    __shared__ float invl[32];
    const int b   = blockIdx.x / (N_ / 32);
    const int n0  = (blockIdx.x % (N_ / 32)) * 32;
    const int tid = threadIdx.x;

    if (tid < 32) invl[tid] = 1.0f / l_arr[(size_t)b * N_ + n0 + tid];
    __syncthreads();

    const float* xb = x    + (size_t)b * C_ * N_ + n0;
    const float* ab = attT + (size_t)b * C_ * N_ + n0;
    for (int e = tid; e < 32 * C_; e += 128) {
        int c = e >> 5, t = e & 31;
        float xv = xb[(size_t)c * N_ + t];
        float au = ab[(size_t)c * N_ + t];
        float xj = fmaxf(xv - au * invl[t], 0.0f);
        u16 h1 = f2bf(xv);
        ch[t * CROW + c] = h1;
        cl[t * CROW + c] = f2bf(xv - bf2f(h1));
        u16 h2 = f2bf(xj);
        ch[t * CROW + C_ + c] = h2;
        cl[t * CROW + C_ + c] = f2bf(xj - bf2f(h2));
    }
    __syncthreads();

    const int lane = tid & 63;
    const int w    = tid >> 6;        // 0..1
    const int col  = lane & 31;       // token within tile
    const int g    = lane >> 5;
    const int m0   = w * 3;           // wave's 3 m-tiles (96 channels)

    f32x16 A[3] = {{0}, {0}, {0}};
#pragma unroll
    for (int ks = 0; ks < 12; ks++) {
        const int k0 = ks * 16;
        short8 bh = *(const short8*)&ch[col * CROW + k0 + g * 8];
        short8 bl = *(const short8*)&cl[col * CROW + k0 + g * 8];
#pragma unroll
        for (int mt = 0; mt < 3; mt++) {
            const size_t wo = (size_t)((m0 + mt) * 12 + ks) * 512 + lane * 8;
            short8 ah = *(const short8*)&wf_hi[wo];
            short8 al = *(const short8*)&wf_lo[wo];
            A[mt] = __builtin_amdgcn_mfma_f32_32x32x16_bf16(ah, bl, A[mt], 0, 0, 0);
            A[mt] = __builtin_amdgcn_mfma_f32_32x32x16_bf16(al, bh, A[mt], 0, 0, 0);
            A[mt] = __builtin_amdgcn_mfma_f32_32x32x16_bf16(ah, bh, A[mt], 0, 0, 0);
        }
    }

    float* yb = y + (size_t)b * COUT_ * N_ + n0 + col;
#pragma unroll
    for (int mt = 0; mt < 3; mt++)
#pragma unroll
        for (int r = 0; r < 16; r++) {
            int o = (m0 + mt) * 32 + (r & 3) + 8 * (r >> 2) + 4 * g;
            yb[(size_t)o * N_] = A[mt][r] + convb[o];
        }
}

// ---------------------------------------------------------------------------
// K4a: per-(b,channel) partial BN sums (distinct output lines, no contention)
__global__ __launch_bounds__(256) void bn_partial(const float* __restrict__ y,
                                                  float* __restrict__ pb) {
    const int o   = blockIdx.x;
    const int b   = blockIdx.y;
    const int tid = threadIdx.x;
    float s = 0.0f, q = 0.0f;
    const float4* p = (const float4*)(y + (size_t)(b * COUT_ + o) * N_);
    for (int i = tid; i < N_ / 4; i += 256) {
        float4 v = p[i];
        s += v.x + v.y + v.z + v.w;
        q += v.x * v.x + v.y * v.y + v.z * v.z + v.w * v.w;
    }
#pragma unroll
    for (int d = 1; d < 64; d <<= 1) {
        s += __shfl_xor(s, d);
        q += __shfl_xor(q, d);
    }
    __shared__ float wss[4], wqq[4];
    if ((tid & 63) == 0) { wss[tid >> 6] = s; wqq[tid >> 6] = q; }
    __syncthreads();
    if (tid == 0) {
        pb[b * COUT_ + o]                = wss[0] + wss[1] + wss[2] + wss[3];
        pb[B_ * COUT_ + b * COUT_ + o]   = wqq[0] + wqq[1] + wqq[2] + wqq[3];
    }
}

// K4b: reduce partials -> scale/shift
__global__ __launch_bounds__(192) void bn_finish(const float* __restrict__ pb,
                                                 const float* __restrict__ gamma,
                                                 const float* __restrict__ beta,
                                                 float* __restrict__ ss) {
    const int o = threadIdx.x;
    float s = 0.0f, q = 0.0f;
#pragma unroll
    for (int b = 0; b < B_; b++) {
        s += pb[b * COUT_ + o];
        q += pb[B_ * COUT_ + b * COUT_ + o];
    }
    const float invn = 1.0f / (float)NTOK_;
    float mean = s * invn;
    float var  = q * invn - mean * mean;
    float sc   = gamma[o] * rsqrtf(var + BN_EPS);
    ss[o]         = sc;
    ss[COUT_ + o] = beta[o] - mean * sc;
}

// K5: y -> BN affine -> exact GELU -> fp32 out
__global__ __launch_bounds__(256) void bn_gelu_out(const float* __restrict__ y,
                                                   const float* __restrict__ ss,
                                                   float* __restrict__ out) {
    const int total4 = (B_ * COUT_ * N_) / 4;
    int i = blockIdx.x * 256 + threadIdx.x;
    if (i >= total4) return;
    int base = i * 4;
    int o = (base / N_) % COUT_;
    float sc = ss[o], sh = ss[COUT_ + o];
    float4 v = *(const float4*)&y[base];
    float u0 = fmaf(v.x, sc, sh), u1 = fmaf(v.y, sc, sh);
    float u2 = fmaf(v.z, sc, sh), u3 = fmaf(v.w, sc, sh);
    const float k = 0.70710678118654752f;
    float4 g;
    g.x = 0.5f * u0 * (1.0f + erff(u0 * k));
    g.y = 0.5f * u1 * (1.0f + erff(u1 * k));
    g.z = 0.5f * u2 * (1.0f + erff(u2 * k));
    g.w = 0.5f * u3 * (1.0f + erff(u3 * k));
    *(float4*)&out[base] = g;
}

// ---------------------------------------------------------------------------
extern "C" void kernel_launch(void* const* d_in, const int* in_sizes, int n_in,
                              void* d_out, int out_size, void* d_ws, size_t ws_size,
                              hipStream_t stream) {
    const float* x     = (const float*)d_in[0];
    const float* w     = (const float*)d_in[1];
    const float* cb    = (const float*)d_in[2];
    const float* gamma = (const float*)d_in[3];
    const float* beta  = (const float*)d_in[4];

    u16* xf_hi = (u16*)d_ws;                         // BNC bf16 (fragment-major)
    u16* xf_lo = xf_hi + (size_t)BNC;                // BNC
    u16* xc_hi = xf_lo + (size_t)BNC;                // BNC (channel-major, V)
    float* attT  = (float*)(xc_hi + (size_t)BNC);    // BNC fp32
    u16* wf_hi = (u16*)(attT + (size_t)BNC);         // 192*192 bf16 (fragment-major)
    u16* wf_lo = wf_hi + COUT_ * 2 * C_;             // 192*192 bf16
    float* y     = (float*)(wf_lo + COUT_ * 2 * C_); // B*COUT*N fp32
    float* ss    = y + (size_t)B_ * COUT_ * N_;      // 2*COUT
    float* l_arr = ss + 2 * COUT_;                   // NTOK
    float* norm2 = l_arr + NTOK_;                    // NTOK
    int*   maxb  = (int*)(norm2 + NTOK_);            // 1 (contiguous after norm2)
    float* pb    = attT;                             // 2*B*COUT partials (attT dead after conv)

    // one memset covers l_arr | norm2 | maxb (contiguous)
    hipMemsetAsync(l_arr, 0, (2 * NTOK_) * sizeof(float) + sizeof(int), stream);
    hipMemsetAsync(attT, 0, (size_t)BNC * sizeof(float), stream);

    transpose_split<<<dim3(N_ / 32, C_ / 32, B_), 256, 0, stream>>>(x, xf_hi, xf_lo, xc_hi, norm2);
    cast_w<<<dim3((COUT_ * 2 * C_ + 255) / 256), 256, 0, stream>>>(w, wf_hi, wf_lo);
    norm_max<<<dim3(25), 256, 0, stream>>>(norm2, maxb);
    flash_attn_mfma32<<<dim3(NBLK2), 256, 0, stream>>>(
        xf_hi, xf_lo, xc_hi, norm2, maxb, attT, l_arr);
    conv_mfma<<<dim3(B_ * (N_ / 32)), 128, 0, stream>>>(x, attT, l_arr, wf_hi, wf_lo, cb, y);
    bn_partial<<<dim3(COUT_, B_), 256, 0, stream>>>(y, pb);
    bn_finish<<<dim3(1), 192, 0, stream>>>(pb, gamma, beta, ss);
    bn_gelu_out<<<dim3((B_ * COUT_ * N_ / 4 + 255) / 256), 256, 0, stream>>>(y, ss, (float*)d_out);
}

// Round 16
// 204.773 us; speedup vs baseline: 1.0215x; 1.0215x over previous
//
#include <hip/hip_runtime.h>
#include <hip/hip_bf16.h>

// Problem constants
#define B_    8
#define C_    96
#define N_    3136      // 56*56
#define COUT_ 192
#define NTOK_ 25088     // B_*N_
#define BN_EPS 1e-5f

#define CROW 200        // conv cat LDS token-row stride in bf16 (192+8): 400B odd*16 -> conflict-free
#define BNC  (B_ * N_ * C_)
#define NSPLIT 3
#define NT98  98        // 32-row K tiles per batch (3136/32)

// K2 LDS per buffer: Kh frags 6KB (frag kc at kc*1024, lane*16 within) |
// V 8KB at +6144 (96 ch x 80B rows + pad). x2 buffers = 28672 B.
#define K2_V_OFF 6144
#define K2_BUFSZ 14336

typedef __hip_bfloat16 bf16;
typedef unsigned short u16;
typedef unsigned int u32;
typedef __attribute__((ext_vector_type(8))) short short8;    // 8 bf16 = 16B (MFMA A/B frag)
typedef __attribute__((ext_vector_type(16))) float f32x16;   // 32x32 MFMA C/D frag

__device__ __forceinline__ u16 f2bf(float f) {
    union { __hip_bfloat16 h; u16 u; } cv;
    cv.h = __float2bfloat16(f);
    return cv.u;
}
__device__ __forceinline__ float bf2f(u16 v) {
    union { u16 u; __hip_bfloat16 h; } cv;
    cv.u = v;
    return __bfloat162float(cv.h);
}
__device__ __forceinline__ u32 packbf2(float lo, float hi) {
    return ((u32)f2bf(hi) << 16) | (u32)f2bf(lo);
}

// async global->LDS DMA, 16B per lane: LDS dest = WAVE-UNIFORM base + lane*16.
__device__ __forceinline__ void gload_lds16(const void* g, void* l) {
    __builtin_amdgcn_global_load_lds((const __attribute__((address_space(1))) void*)g,
                                     (__attribute__((address_space(3))) void*)l,
                                     16, 0, 0);
}

// fragment offset in xf arrays: frag (b-pre-offset pointer, tile t, chunk kc)
// = ((t*6)+kc) * 512 u16 (1KB). Lane l holds token t*32+(l&31),
// channels kc*16+(l>>5)*8 .. +8 — exactly the mfma_32x32x16 A/B layout.
__device__ __forceinline__ size_t foff(int t, int kc) {
    return ((size_t)t * 6 + kc) << 9;
}

// ---------------------------------------------------------------------------
// K1: x [B][C][N] fp32 ->
//   xf_hi/xf_lo [B][98][6][512] bf16 fragment-major (K and Q frags, hi/lo)
//   xc_hi [B][C][N] bf16 (channel-major, V staged from here)
//   norm2 per-token squared norms.  (R20 version — HW-verified.)
__global__ __launch_bounds__(256) void transpose_split(const float* __restrict__ x,
                                                       u16* __restrict__ xf_hi,
                                                       u16* __restrict__ xf_lo,
                                                       u16* __restrict__ xc_hi,
                                                       float* __restrict__ norm2) {
    __shared__ float tile[32][33];
    __shared__ float nrm[32];
    const int nb = blockIdx.x * 32;     // token base (tile t = nb/32)
    const int cb = blockIdx.y * 32;     // channel base (kc = cb/16 + {0,1})
    const int b  = blockIdx.z;
    const int tid = threadIdx.x;
    const int tx = tid & 31;
    const int ty = tid >> 5;
    if (tid < 32) nrm[tid] = 0.0f;
    float psum = 0.0f;
#pragma unroll
    for (int r = 0; r < 32; r += 8) {
        size_t idx = ((size_t)b * C_ + cb + ty + r) * N_ + nb + tx;
        float v = x[idx];
        tile[ty + r][tx] = v;
        xc_hi[idx] = f2bf(v);
        psum = fmaf(v, v, psum);
    }
    __syncthreads();               // tile visible; nrm init done
    atomicAdd(&nrm[tx], psum);     // LDS atomic, 8 adders per slot

    // phase 2: fragment-major hi/lo writes. 128 items (kc_i in 0..1, lane l
    // in 0..63); threads 0-127 write hi, 128-255 write lo. 16B/thread.
    {
        const int item  = tid & 127;
        const int is_lo = tid >> 7;
        const int kc_i  = item >> 6;
        const int l     = item & 63;
        const int kcg   = (cb >> 4) + kc_i;
        union { u16 a[8]; short8 v8; } o;
#pragma unroll
        for (int j = 0; j < 8; j++) {
            float v = tile[kc_i * 16 + ((l >> 5) * 8) + j][l & 31];
            u16 h = f2bf(v);
            o.a[j] = is_lo ? f2bf(v - bf2f(h)) : h;
        }
        u16* dst = (is_lo ? xf_lo : xf_hi) +
                   ((size_t)b * NT98 * 6 << 9) + foff(nb >> 5, kcg) + l * 8;
        *(short8*)dst = o.v8;
    }
    __syncthreads();               // nrm complete
    if (tid < 32)
        atomicAdd(&norm2[(size_t)b * N_ + nb + tid], nrm[tid]);
}

// K1b: conv_w [O][2C] fp32 -> wf_hi/wf_lo bf16 FRAGMENT-MAJOR (R23, verified:
// -9.5us total via coalesced conv weight loads).
__global__ __launch_bounds__(256) void cast_w(const float* __restrict__ w,
                                              u16* __restrict__ wf_hi,
                                              u16* __restrict__ wf_lo) {
    int i = blockIdx.x * 256 + threadIdx.x;
    if (i >= COUT_ * 2 * C_) return;
    float v = w[i];
    u16 h  = f2bf(v);
    u16 lo = f2bf(v - bf2f(h));
    int o = i / (2 * C_), c = i % (2 * C_);
    int mt = o >> 5, lrow = o & 31;
    int ks = c >> 4, hi8 = (c >> 3) & 1, j = c & 7;
    size_t d = ((size_t)(mt * 12 + ks) * 64 + hi8 * 32 + lrow) * 8 + j;
    wf_hi[d] = h;
    wf_lo[d] = lo;
}

// K1c: global max of norm2 — multi-block; norm2>=0 -> int-bits atomicMax.
__global__ __launch_bounds__(256) void norm_max(const float* __restrict__ norm2,
                                                int* __restrict__ maxbits) {
    const int tid = blockIdx.x * 256 + threadIdx.x;
    float m = 0.0f;
    for (int i = tid; i < NTOK_; i += gridDim.x * 256) m = fmaxf(m, norm2[i]);
#pragma unroll
    for (int d = 1; d < 64; d <<= 1) m = fmaxf(m, __shfl_xor(m, d));
    if ((threadIdx.x & 63) == 0) atomicMax(maxbits, __float_as_int(m));
}

// ---------------------------------------------------------------------------
// K2: MFMA flash attention, transposed-S, 3-way split-K.
// FROZEN R22 body (89.5us stable across 5 sessions, conflicts 0).
// Structurally bound by the per-tile serial chain (QK->softmax->PV->barrier):
// four variants (all-LDS, K-direct, hybrid, balanced-768 w/ 3x HBM traffic)
// all converge at 89.5-90.5us. R26's flat queue fixed balance (occ 26%) but
// destroyed lockstep-kt L2 sharing (FETCH 60->197MB) — net zero; reverted.
__global__ __launch_bounds__(256, 3) void flash_attn_mfma32(const u16* __restrict__ xf_hi,
                                                            const u16* __restrict__ xf_lo,
                                                            const u16* __restrict__ xc_hi,
                                                            const float* __restrict__ norm2,
                                                            const int* __restrict__ maxbits,
                                                            float* __restrict__ attT,
                                                            float* __restrict__ l_arr) {
    __shared__ __align__(16) char LDSU[2][K2_BUFSZ];
    const int b     = blockIdx.y;
    const int i0    = blockIdx.x * 128;
    const int split = blockIdx.z;
    const int kt0   = (NT98 * split) / NSPLIT;
    const int kt1   = (NT98 * (split + 1)) / NSPLIT;
    const int tid   = threadIdx.x;
    const int lane  = tid & 63;
    const int w     = tid >> 6;
    const int col   = lane & 31;
    const int g     = lane >> 5;

    const u16* fh = xf_hi + ((size_t)b * NT98 * 6 << 9);
    const u16* fl = xf_lo + ((size_t)b * NT98 * 6 << 9);
    const u16* vh = xc_hi + (size_t)b * C_ * N_;

    // 14 DMA slots of 1KB per buffer: Kh 0..5 (contiguous from xf_hi),
    // V 6..13 (80B-row pattern from xc_hi). Wave w owns slots w+4j.
    u32 loff[4], dofs[4];
#pragma unroll
    for (int j = 0; j < 4; j++) {
        int s = w + 4 * j;
        if (s >= 14) { loff[j] = 0; dofs[j] = 0; continue; }
        if (s < 6) {                  // Kh: contiguous 1KB slots
            loff[j] = (u32)(s * 1024 + lane * 16);
            dofs[j] = (u32)(s * 1024);
        } else {                      // V
            int t = s - 6;
            int p = t * 64 + lane;    // 16B chunk 0..511 (480 data + pad)
            int ch = p / 5, c = p % 5;
            if (c > 3) c = 3;
            loff[j] = (ch < 96) ? (u32)(ch * (N_ * 2) + c * 16) : 0u;
            dofs[j] = (u32)(K2_V_OFF + t * 1024);
        }
    }

    // Q frags: coalesced dwordx4 from fragment-major arrays, once
    int qt = blockIdx.x * 4 + w;
    if (qt > NT98 - 1) qt = NT98 - 1;
    const int qrow  = i0 + w * 32 + col;
    const int qrowc = qrow < N_ ? qrow : N_ - 1;
    short8 qh[6], ql[6];
#pragma unroll
    for (int kc = 0; kc < 6; kc++) {
        qh[kc] = *(const short8*)&fh[foff(qt, kc) + lane * 8];
        ql[kc] = *(const short8*)&fl[foff(qt, kc) + lane * 8];
    }
    const float maxn2 = __int_as_float(*maxbits);
    const float m_i   = sqrtf(norm2[(size_t)b * N_ + qrowc] * maxn2);
    float l_acc = 0.0f;
    f32x16 O0 = {0}, O1 = {0}, O2 = {0};

    // stage tile kt (Kh + V) into buffer nbuf (async DMA)
    auto stage = [&](int nbuf, int kt) {
        const u32 ktK = (u32)kt * 6144u;   // Kh: 6KB contiguous per tile
        const u32 ktV = (u32)kt * 64u;     // V: 32 tokens * 2B
#pragma unroll
        for (int j = 0; j < 4; j++) {
            int s = w + 4 * j;
            if (s >= 14) break;
            const char* sb = (s < 6) ? (const char*)fh + ktK
                                     : (const char*)vh + ktV;
            gload_lds16(sb + loff[j], (char*)&LDSU[nbuf][0] + dofs[j]);
        }
    };

    stage(0, kt0);
    __syncthreads();

    const int g16 = g * 16;
    int buf = 0;
    for (int kt = kt0; kt < kt1; kt++) {
        // (1) prefetch next tile into back buffer
        if (kt + 1 < kt1) stage(buf ^ 1, kt + 1);

        const char* Lb = (const char*)&LDSU[buf][0];

        // (2) Kl frags direct from global (coalesced, L1-hot) — issued
        //     before the MFMA chain so latency hides under Kh/QK work.
        short8 kl[6];
#pragma unroll
        for (int kc = 0; kc < 6; kc++)
            kl[kc] = *(const short8*)&fl[foff(kt, kc) + lane * 8];

        // (3) QK^T: Kh from LDS (sequential lane*16 — conflict-free)
        f32x16 S = {0};
        __builtin_amdgcn_s_setprio(1);
#pragma unroll
        for (int kc = 0; kc < 6; kc++) {
            short8 kh = *(const short8*)(Lb + kc * 1024 + lane * 16);
            S = __builtin_amdgcn_mfma_f32_32x32x16_bf16(kh, ql[kc], S, 0, 0, 0);
            S = __builtin_amdgcn_mfma_f32_32x32x16_bf16(kl[kc], qh[kc], S, 0, 0, 0);
            S = __builtin_amdgcn_mfma_f32_32x32x16_bf16(kh, qh[kc], S, 0, 0, 0);
        }
        __builtin_amdgcn_s_setprio(0);

        // (4) softmax numerators + bf16 pack
        float p[16];
#pragma unroll
        for (int r = 0; r < 16; r++) {
            p[r] = __expf(S[r] - m_i);
            l_acc += p[r];
        }
        u32 w8[8];
#pragma unroll
        for (int q = 0; q < 8; q++) w8[q] = packbf2(p[2 * q], p[2 * q + 1]);

        // (5) PV from V-LDS (80B rows: conflict-free)
        __builtin_amdgcn_s_setprio(1);
#pragma unroll
        for (int kc = 0; kc < 2; kc++) {
            const int qb = kc * 4;
            u32 a0 = w8[qb + 0], a1 = w8[qb + 1];
            u32 a2 = w8[qb + 2], a3 = w8[qb + 3];
            u32 s0 = __shfl_xor((int)a0, 32), s1 = __shfl_xor((int)a1, 32);
            u32 s2 = __shfl_xor((int)a2, 32), s3 = __shfl_xor((int)a3, 32);
            union { short8 v; u32 u[4]; } Bf;
            Bf.u[0] = g ? s2 : a0;
            Bf.u[1] = g ? s3 : a1;
            Bf.u[2] = g ? a2 : s0;
            Bf.u[3] = g ? a3 : s1;
            const int vo = K2_V_OFF + col * 80 + kc * 32 + g16;
            short8 v0 = *(const short8*)(Lb + vo);
            short8 v1 = *(const short8*)(Lb + vo + 2560);   // +32 ch
            short8 v2 = *(const short8*)(Lb + vo + 5120);   // +64 ch
            O0 = __builtin_amdgcn_mfma_f32_32x32x16_bf16(v0, Bf.v, O0, 0, 0, 0);
            O1 = __builtin_amdgcn_mfma_f32_32x32x16_bf16(v1, Bf.v, O1, 0, 0, 0);
            O2 = __builtin_amdgcn_mfma_f32_32x32x16_bf16(v2, Bf.v, O2, 0, 0, 0);
        }
        __builtin_amdgcn_s_setprio(0);

        __syncthreads();     // drains my DMAs + all waves' LDS reads done
        buf ^= 1;
    }

    if (qrow < N_) {
        float* ab = attT + (size_t)b * C_ * N_ + qrow;
#pragma unroll
        for (int r = 0; r < 16; r++) {
            int c = (r & 3) + 8 * (r >> 2) + 4 * g;
            atomicAdd(&ab[(size_t)(c)      * N_], O0[r]);
            atomicAdd(&ab[(size_t)(c + 32) * N_], O1[r]);
            atomicAdd(&ab[(size_t)(c + 64) * N_], O2[r]);
        }
        float l_tot = l_acc + __shfl_xor(l_acc, 32);
        if (g == 0) atomicAdd(&l_arr[(size_t)b * N_ + qrow], l_tot);
    }
}

// ---------------------------------------------------------------------------
// K3: MFMA 1x1 conv (R23 version — fragment-major weights, plain epilogue).
__global__ __launch_bounds__(128, 3) void conv_mfma(const float* __restrict__ x,
                                                    const float* __restrict__ attT,
                                                    const float* __restrict__ l_arr,
                                                    const u16* __restrict__ wf_hi,
                                                    const u16* __restrict__ wf_lo,
                                                    const float* __restrict__ convb,
                                                    float* __restrict__ y) {
    __shared__ u16 ch[32 * CROW];
    __shared__ u16 cl[32 * CROW];
    __shared__ float invl[32];
    const int b   = blockIdx.x / (N_ / 32);
    const int n0  = (blockIdx.x % (N_ / 32)) * 32;
    const int tid = threadIdx.x;

    if (tid < 32) invl[tid] = 1.0f / l_arr[(size_t)b * N_ + n0 + tid];
    __syncthreads();

    const float* xb = x    + (size_t)b * C_ * N_ + n0;
    const float* ab = attT + (size_t)b * C_ * N_ + n0;
    for (int e = tid; e < 32 * C_; e += 128) {
        int c = e >> 5, t = e & 31;
        float xv = xb[(size_t)c * N_ + t];
        float au = ab[(size_t)c * N_ + t];
        float xj = fmaxf(xv - au * invl[t], 0.0f);
        u16 h1 = f2bf(xv);
        ch[t * CROW + c] = h1;
        cl[t * CROW + c] = f2bf(xv - bf2f(h1));
        u16 h2 = f2bf(xj);
        ch[t * CROW + C_ + c] = h2;
        cl[t * CROW + C_ + c] = f2bf(xj - bf2f(h2));
    }
    __syncthreads();

    const int lane = tid & 63;
    const int w    = tid >> 6;        // 0..1
    const int col  = lane & 31;       // token within tile
    const int g    = lane >> 5;
    const int m0   = w * 3;           // wave's 3 m-tiles (96 channels)

    f32x16 A[3] = {{0}, {0}, {0}};
#pragma unroll
    for (int ks = 0; ks < 12; ks++) {
        const int k0 = ks * 16;
        short8 bh = *(const short8*)&ch[col * CROW + k0 + g * 8];
        short8 bl = *(const short8*)&cl[col * CROW + k0 + g * 8];
#pragma unroll
        for (int mt = 0; mt < 3; mt++) {
            const size_t wo = (size_t)((m0 + mt) * 12 + ks) * 512 + lane * 8;
            short8 ah = *(const short8*)&wf_hi[wo];
            short8 al = *(const short8*)&wf_lo[wo];
            A[mt] = __builtin_amdgcn_mfma_f32_32x32x16_bf16(ah, bl, A[mt], 0, 0, 0);
            A[mt] = __builtin_amdgcn_mfma_f32_32x32x16_bf16(al, bh, A[mt], 0, 0, 0);
            A[mt] = __builtin_amdgcn_mfma_f32_32x32x16_bf16(ah, bh, A[mt], 0, 0, 0);
        }
    }

    float* yb = y + (size_t)b * COUT_ * N_ + n0 + col;
#pragma unroll
    for (int mt = 0; mt < 3; mt++)
#pragma unroll
        for (int r = 0; r < 16; r++) {
            int o = (m0 + mt) * 32 + (r & 3) + 8 * (r >> 2) + 4 * g;
            yb[(size_t)o * N_] = A[mt][r] + convb[o];
        }
}

// ---------------------------------------------------------------------------
// K4a: per-(b,channel) partial BN sums (distinct output lines, no contention)
__global__ __launch_bounds__(256) void bn_partial(const float* __restrict__ y,
                                                  float* __restrict__ pb) {
    const int o   = blockIdx.x;
    const int b   = blockIdx.y;
    const int tid = threadIdx.x;
    float s = 0.0f, q = 0.0f;
    const float4* p = (const float4*)(y + (size_t)(b * COUT_ + o) * N_);
    for (int i = tid; i < N_ / 4; i += 256) {
        float4 v = p[i];
        s += v.x + v.y + v.z + v.w;
        q += v.x * v.x + v.y * v.y + v.z * v.z + v.w * v.w;
    }
#pragma unroll
    for (int d = 1; d < 64; d <<= 1) {
        s += __shfl_xor(s, d);
        q += __shfl_xor(q, d);
    }
    __shared__ float wss[4], wqq[4];
    if ((tid & 63) == 0) { wss[tid >> 6] = s; wqq[tid >> 6] = q; }
    __syncthreads();
    if (tid == 0) {
        pb[b * COUT_ + o]                = wss[0] + wss[1] + wss[2] + wss[3];
        pb[B_ * COUT_ + b * COUT_ + o]   = wqq[0] + wqq[1] + wqq[2] + wqq[3];
    }
}

// K4b: reduce partials -> scale/shift
__global__ __launch_bounds__(192) void bn_finish(const float* __restrict__ pb,
                                                 const float* __restrict__ gamma,
                                                 const float* __restrict__ beta,
                                                 float* __restrict__ ss) {
    const int o = threadIdx.x;
    float s = 0.0f, q = 0.0f;
#pragma unroll
    for (int b = 0; b < B_; b++) {
        s += pb[b * COUT_ + o];
        q += pb[B_ * COUT_ + b * COUT_ + o];
    }
    const float invn = 1.0f / (float)NTOK_;
    float mean = s * invn;
    float var  = q * invn - mean * mean;
    float sc   = gamma[o] * rsqrtf(var + BN_EPS);
    ss[o]         = sc;
    ss[COUT_ + o] = beta[o] - mean * sc;
}

// K5: y -> BN affine -> exact GELU -> fp32 out
__global__ __launch_bounds__(256) void bn_gelu_out(const float* __restrict__ y,
                                                   const float* __restrict__ ss,
                                                   float* __restrict__ out) {
    const int total4 = (B_ * COUT_ * N_) / 4;
    int i = blockIdx.x * 256 + threadIdx.x;
    if (i >= total4) return;
    int base = i * 4;
    int o = (base / N_) % COUT_;
    float sc = ss[o], sh = ss[COUT_ + o];
    float4 v = *(const float4*)&y[base];
    float u0 = fmaf(v.x, sc, sh), u1 = fmaf(v.y, sc, sh);
    float u2 = fmaf(v.z, sc, sh), u3 = fmaf(v.w, sc, sh);
    const float k = 0.70710678118654752f;
    float4 g;
    g.x = 0.5f * u0 * (1.0f + erff(u0 * k));
    g.y = 0.5f * u1 * (1.0f + erff(u1 * k));
    g.z = 0.5f * u2 * (1.0f + erff(u2 * k));
    g.w = 0.5f * u3 * (1.0f + erff(u3 * k));
    *(float4*)&out[base] = g;
}

// ---------------------------------------------------------------------------
extern "C" void kernel_launch(void* const* d_in, const int* in_sizes, int n_in,
                              void* d_out, int out_size, void* d_ws, size_t ws_size,
                              hipStream_t stream) {
    const float* x     = (const float*)d_in[0];
    const float* w     = (const float*)d_in[1];
    const float* cb    = (const float*)d_in[2];
    const float* gamma = (const float*)d_in[3];
    const float* beta  = (const float*)d_in[4];

    u16* xf_hi = (u16*)d_ws;                         // BNC bf16 (fragment-major)
    u16* xf_lo = xf_hi + (size_t)BNC;                // BNC
    u16* xc_hi = xf_lo + (size_t)BNC;                // BNC (channel-major, V)
    float* attT  = (float*)(xc_hi + (size_t)BNC);    // BNC fp32
    u16* wf_hi = (u16*)(attT + (size_t)BNC);         // 192*192 bf16 (fragment-major)
    u16* wf_lo = wf_hi + COUT_ * 2 * C_;             // 192*192 bf16
    float* y     = (float*)(wf_lo + COUT_ * 2 * C_); // B*COUT*N fp32
    float* ss    = y + (size_t)B_ * COUT_ * N_;      // 2*COUT
    float* l_arr = ss + 2 * COUT_;                   // NTOK
    float* norm2 = l_arr + NTOK_;                    // NTOK
    int*   maxb  = (int*)(norm2 + NTOK_);            // 1 (contiguous after norm2)
    float* pb    = attT;                             // 2*B*COUT partials (attT dead after conv)

    // one memset covers l_arr | norm2 | maxb (contiguous)
    hipMemsetAsync(l_arr, 0, (2 * NTOK_) * sizeof(float) + sizeof(int), stream);
    hipMemsetAsync(attT, 0, (size_t)BNC * sizeof(float), stream);

    transpose_split<<<dim3(N_ / 32, C_ / 32, B_), 256, 0, stream>>>(x, xf_hi, xf_lo, xc_hi, norm2);
    cast_w<<<dim3((COUT_ * 2 * C_ + 255) / 256), 256, 0, stream>>>(w, wf_hi, wf_lo);
    norm_max<<<dim3(25), 256, 0, stream>>>(norm2, maxb);
    flash_attn_mfma32<<<dim3((N_ + 127) / 128, B_, NSPLIT), 256, 0, stream>>>(
        xf_hi, xf_lo, xc_hi, norm2, maxb, attT, l_arr);
    conv_mfma<<<dim3(B_ * (N_ / 32)), 128, 0, stream>>>(x, attT, l_arr, wf_hi, wf_lo, cb, y);
    bn_partial<<<dim3(COUT_, B_), 256, 0, stream>>>(y, pb);
    bn_finish<<<dim3(1), 192, 0, stream>>>(pb, gamma, beta, ss);
    bn_gelu_out<<<dim3((B_ * COUT_ * N_ / 4 + 255) / 256), 256, 0, stream>>>(y, ss, (float*)d_out);
}